// Round 13
// baseline (230.915 us; speedup 1.0000x reference)
//
#include <hip/hip_runtime.h>

// out[b,o] = sum_h W2[o,h]*leaky(h) + b2[o],  h = W1[o]·x[b] + b1[o]
// leaky(t) = 0.6t + 0.4|t|
//   out[b,o] = 0.6(v[o]·x[b] + c0[o]) + b2[o] + sum_h (0.4 W2[o,h])|h|
// R14: 32x32x16 MFMA (K=16 exact, full-rate m119 family), 256 WGs (1/CU).
// stage1: D1 = mfma32(A=W1frag, B=xfrag, C=b1-bcast) -> lane holds 16 h for
//   its own b=lane&31 (D layout m74/m101: row=(reg&3)+8*(reg>>2)+4*(lane>>5)).
// stage2: 2x mfma32(A=pack(|d regs 0-7 / 8-15|), B=0.4*W2 bcast, acc) per ht.
// linear: acc init = mfma32(A=xf, B=0.6v bcast, C=c0 splat).
// W1 frags hoisted to 64 VGPRs; b1/W2/v via LDS broadcast (same-addr free).

#define B_DIM 32768
#define I_DIM 16
#define O_DIM 16
#define H_DIM 512

typedef _Float16 f16x8  __attribute__((ext_vector_type(8)));
typedef __fp16   h16x2  __attribute__((ext_vector_type(2)));
typedef float    f32x4  __attribute__((ext_vector_type(4)));
typedef float    f32x16 __attribute__((ext_vector_type(16)));
typedef int      i32x4  __attribute__((ext_vector_type(4)));

// 256 blocks x 512 thr (8 waves) = exactly 1 block/CU. o=blk&15, grp=blk>>4.
// Block covers 64 b32-tiles; wave w: 8 jobs, tile = grp*64 + w*8 + jj.
__global__ __launch_bounds__(512, 2) void mlp_fused(
    const float* __restrict__ x, const float* __restrict__ W1,
    const float* __restrict__ b1, const float* __restrict__ W2,
    const float* __restrict__ b2, float* __restrict__ out) {
    __shared__ f16x8 sm_a1[1024];                 // [ht][lane] W1 frags 16 KiB
    __shared__ __align__(16) f16x8 sm_w2[64];     // [ht][s][hi] compact 1 KiB
    __shared__ __align__(64) float sm_bc[512];    // [ht][hi][reg] b1 perm 2 KiB
    __shared__ float red[512];
    __shared__ float v_sm[16];
    __shared__ __align__(16) _Float16 vl_sm[16];
    __shared__ float c_sm;

    const int tid = threadIdx.x;
    const int o   = blockIdx.x & 15;
    const int grp = blockIdx.x >> 4;
    const float* W1o = W1 + (size_t)o * H_DIM * I_DIM;
    const float* W2o = W2 + (size_t)o * H_DIM;
    const float* b1o = b1 + (size_t)o * H_DIM;

    // ---- phase A: staging ----
#pragma unroll
    for (int i = 0; i < 2; ++i) {
        const int e = tid + 512 * i;              // [ht][lane]
        const int l = e & 63, ht = e >> 6;
        const int row = l & 31, hi = l >> 5;
        const float* src = W1o + (size_t)(ht * 32 + row) * I_DIM + hi * 8;
        f16x8 v;
#pragma unroll
        for (int j = 0; j < 8; ++j) v[j] = (_Float16)src[j];
        sm_a1[e] = v;
    }
    if (tid < 64) {
        // stage2-B compact frag: elem j <-> k=hi*8+j <-> h = ht*32+s*16+R(j,hi)
        const int hi = tid & 1, s = (tid >> 1) & 1, ht = tid >> 2;
        f16x8 v;
#pragma unroll
        for (int j = 0; j < 8; ++j) {
            const int h = ht * 32 + s * 16 + (j & 3) + 8 * (j >> 2) + 4 * hi;
            v[j] = (_Float16)(0.4f * W2o[h]);
        }
        sm_w2[(ht * 2 + s) * 2 + hi] = v;
    }
    {   // b1 permuted to C layout: [ht][hi][reg] = b1[ht*32 + R(reg,hi)]
        const int reg = tid & 15, hi = (tid >> 4) & 1, ht = tid >> 5;
        sm_bc[tid] = b1o[ht * 32 + (reg & 3) + 8 * (reg >> 2) + 4 * hi];
    }
    {   // v[i] = 0.6 sum_h W2[h]W1[h,i]
        const int i = tid & 15, hc = tid >> 4;    // 32 chunks x 16 h
        float acc = 0.f;
#pragma unroll
        for (int hh = 0; hh < 16; ++hh) {
            const int h = hc * 16 + hh;
            acc = fmaf(W2o[h], W1o[(size_t)h * I_DIM + i], acc);
        }
        red[tid] = acc;
    }
    __syncthreads();
    if (tid < 16) {
        float s = 0.f;
#pragma unroll
        for (int k = 0; k < 32; ++k) s += red[tid + 16 * k];
        v_sm[tid] = 0.6f * s;
    }
    float cpart = W2o[tid] * b1o[tid];
    __syncthreads();
    red[tid] = cpart;
    __syncthreads();
    if (tid < 64) {
        float s = 0.f;
#pragma unroll
        for (int k = 0; k < 8; ++k) s += red[tid + 64 * k];
#pragma unroll
        for (int m = 1; m <= 32; m <<= 1) s += __shfl_xor(s, m, 64);
        if (tid == 0) c_sm = 0.6f * s + b2[o];
    }
    if (tid < 16) vl_sm[tid] = (_Float16)v_sm[tid];   // own-thread v_sm, no race
    __syncthreads();

    // ---- phase B ----
    const int lane = tid & 63, w = tid >> 6;
    const int c = lane & 31, hi = lane >> 5;
    const bool wr = (hi == ((c >> 2) & 1));           // writer lane for b=c
    const float c0 = c_sm;
    const f16x8 vlf = *reinterpret_cast<const f16x8*>(&vl_sm[hi * 8]);

    // hoist W1 fragments to registers (64 VGPR)
    f16x8 A1r[16];
#pragma unroll
    for (int ht = 0; ht < 16; ++ht) A1r[ht] = sm_a1[ht * 64 + lane];

    f32x16 cvec;
#pragma unroll
    for (int r = 0; r < 16; ++r) cvec[r] = c0;

    for (int jj = 0; jj < 8; ++jj) {
        const int tile = grp * 64 + w * 8 + jj;
        // x frag: 8 consecutive f32 -> f16x8 (wave reads 2KB contiguous)
        const float* xp = x + (size_t)(tile * 32 + c) * I_DIM + hi * 8;
        const f32x4 x0 = *reinterpret_cast<const f32x4*>(xp);
        const f32x4 x1 = *reinterpret_cast<const f32x4*>(xp + 4);
        h16x2 q0 = __builtin_amdgcn_cvt_pkrtz(x0[0], x0[1]);
        h16x2 q1 = __builtin_amdgcn_cvt_pkrtz(x0[2], x0[3]);
        h16x2 q2 = __builtin_amdgcn_cvt_pkrtz(x1[0], x1[1]);
        h16x2 q3 = __builtin_amdgcn_cvt_pkrtz(x1[2], x1[3]);
        i32x4 xi;
        xi[0] = __builtin_bit_cast(int, q0); xi[1] = __builtin_bit_cast(int, q1);
        xi[2] = __builtin_bit_cast(int, q2); xi[3] = __builtin_bit_cast(int, q3);
        const f16x8 xf = __builtin_bit_cast(f16x8, xi);

        // linear part: rows=b via A=xf; B = 0.6v bcast; C = c0 splat
        f32x16 accE = __builtin_amdgcn_mfma_f32_32x32x16_f16(xf, vlf, cvec, 0, 0, 0);
        f32x16 accO = {};

#pragma unroll
        for (int ht = 0; ht < 16; ++ht) {
            // bias C: broadcast read (addr depends on hi only)
            const f32x4* bcp = reinterpret_cast<const f32x4*>(&sm_bc[(ht * 2 + hi) * 16]);
            const f32x4 b0 = bcp[0], b1v = bcp[1], b2v = bcp[2], b3v = bcp[3];
            f32x16 bC;
#pragma unroll
            for (int q = 0; q < 4; ++q) {
                bC[q] = b0[q]; bC[4 + q] = b1v[q]; bC[8 + q] = b2v[q]; bC[12 + q] = b3v[q];
            }
            // stage1: D1[h][b], lane holds 16 h (rows R(reg,hi)) for b=c
            const f32x16 d = __builtin_amdgcn_mfma_f32_32x32x16_f16(A1r[ht], xf, bC, 0, 0, 0);
            // pack |d| regs 0-7 -> A2a, regs 8-15 -> A2b
            h16x2 p0 = __builtin_amdgcn_cvt_pkrtz(fabsf(d[0]),  fabsf(d[1]));
            h16x2 p1 = __builtin_amdgcn_cvt_pkrtz(fabsf(d[2]),  fabsf(d[3]));
            h16x2 p2 = __builtin_amdgcn_cvt_pkrtz(fabsf(d[4]),  fabsf(d[5]));
            h16x2 p3 = __builtin_amdgcn_cvt_pkrtz(fabsf(d[6]),  fabsf(d[7]));
            h16x2 p4 = __builtin_amdgcn_cvt_pkrtz(fabsf(d[8]),  fabsf(d[9]));
            h16x2 p5 = __builtin_amdgcn_cvt_pkrtz(fabsf(d[10]), fabsf(d[11]));
            h16x2 p6 = __builtin_amdgcn_cvt_pkrtz(fabsf(d[12]), fabsf(d[13]));
            h16x2 p7 = __builtin_amdgcn_cvt_pkrtz(fabsf(d[14]), fabsf(d[15]));
            i32x4 ia, ib;
            ia[0] = __builtin_bit_cast(int, p0); ia[1] = __builtin_bit_cast(int, p1);
            ia[2] = __builtin_bit_cast(int, p2); ia[3] = __builtin_bit_cast(int, p3);
            ib[0] = __builtin_bit_cast(int, p4); ib[1] = __builtin_bit_cast(int, p5);
            ib[2] = __builtin_bit_cast(int, p6); ib[3] = __builtin_bit_cast(int, p7);
            const f16x8 A2a = __builtin_bit_cast(f16x8, ia);
            const f16x8 A2b = __builtin_bit_cast(f16x8, ib);
            // stage2-B: broadcast reads
            const f16x8 B2a = sm_w2[(ht * 2 + 0) * 2 + hi];
            const f16x8 B2b = sm_w2[(ht * 2 + 1) * 2 + hi];
            if (ht & 1) {
                accO = __builtin_amdgcn_mfma_f32_32x32x16_f16(A2a, B2a, accO, 0, 0, 0);
                accO = __builtin_amdgcn_mfma_f32_32x32x16_f16(A2b, B2b, accO, 0, 0, 0);
            } else {
                accE = __builtin_amdgcn_mfma_f32_32x32x16_f16(A2a, B2a, accE, 0, 0, 0);
                accE = __builtin_amdgcn_mfma_f32_32x32x16_f16(A2b, B2b, accE, 0, 0, 0);
            }
        }

        // epilogue: writer lane b=c takes reg r=(b&3)|((b>>3)<<2) via static tree
        const f32x16 a = accE + accO;
        const bool s0 = (c & 1) != 0, s1 = (c & 2) != 0;
        const bool s2 = (c & 8) != 0, s3 = (c & 16) != 0;
        float u8[8];
#pragma unroll
        for (int m = 0; m < 8; ++m) u8[m] = s0 ? a[2 * m + 1] : a[2 * m];
        float u4[4];
#pragma unroll
        for (int m = 0; m < 4; ++m) u4[m] = s1 ? u8[2 * m + 1] : u8[2 * m];
        float u2[2];
#pragma unroll
        for (int m = 0; m < 2; ++m) u2[m] = s2 ? u4[2 * m + 1] : u4[2 * m];
        const float u1 = s3 ? u2[1] : u2[0];
        if (wr) out[(size_t)(tile * 32 + c) * O_DIM + o] = u1;
    }
}

extern "C" void kernel_launch(void* const* d_in, const int* in_sizes, int n_in,
                              void* d_out, int out_size, void* d_ws, size_t ws_size,
                              hipStream_t stream) {
    const float* x  = (const float*)d_in[0];
    const float* W1 = (const float*)d_in[1];
    const float* b1 = (const float*)d_in[2];
    const float* W2 = (const float*)d_in[3];
    const float* b2 = (const float*)d_in[4];
    float* out = (float*)d_out;

    mlp_fused<<<256, 512, 0, stream>>>(x, W1, b1, W2, b2, out);
}